// Round 4
// baseline (144.546 us; speedup 1.0000x reference)
//
#include <hip/hip_runtime.h>
#include <hip/hip_bf16.h>
#include <stdint.h>

#define HIDDEN 1024
#define SEQL   2048
#define NB     2
#define NH     16
#define DH     64
#define MTOT   (NB * SEQL)   // 4096
#define QKVLD  3072          // fused QKV row stride
#define SCALE_Q 0.18033688011112042f   // 0.125 * log2(e)
#define SPLITS 2
#define KSPAN  (SEQL / SPLITS)         // 1024 k per split-block

typedef __bf16 bf16x8 __attribute__((ext_vector_type(8)));
typedef __bf16 bf16x4 __attribute__((ext_vector_type(4)));
typedef float  f32x4  __attribute__((ext_vector_type(4)));
typedef float  f32x16 __attribute__((ext_vector_type(16)));

__device__ __forceinline__ void gload16(const void* g, void* l) {
    __builtin_amdgcn_global_load_lds(
        (const __attribute__((address_space(1))) void*)g,
        (__attribute__((address_space(3))) void*)l, 16, 0, 0);
}
__device__ __forceinline__ float exp2fast(float x) {
    float r;
    asm("v_exp_f32 %0, %1" : "=v"(r) : "v"(x));
    return r;
}
__device__ __forceinline__ unsigned cvtpk(float lo, float hi) {
    unsigned r;
    asm("v_cvt_pk_bf16_f32 %0, %1, %2" : "=v"(r) : "v"(lo), "v"(hi));
    return r;
}
__device__ __forceinline__ void pswap(unsigned& a, unsigned& b) {
    asm volatile("v_permlane32_swap_b32 %0, %1" : "+v"(a), "+v"(b));
}

// ---------------------------------------------------------------- converts
__global__ void cvt_f32_bf16(const float* __restrict__ src,
                             __bf16* __restrict__ dst, int n4) {
    int i = blockIdx.x * blockDim.x + threadIdx.x;
    if (i < n4) {
        float4 v = reinterpret_cast<const float4*>(src)[i];
        bf16x4 o = { (__bf16)v.x, (__bf16)v.y, (__bf16)v.z, (__bf16)v.w };
        reinterpret_cast<bf16x4*>(dst)[i] = o;
    }
}

// 4 weight matrices -> one contiguous bf16 region [Wq*s | Wk | Wv | Wd]
__global__ void cvt_w4(const float* __restrict__ Wq, const float* __restrict__ Wk,
                       const float* __restrict__ Wv, const float* __restrict__ Wd,
                       __bf16* __restrict__ dst) {
    int seg = blockIdx.y;
    const float* src = seg == 0 ? Wq : seg == 1 ? Wk : seg == 2 ? Wv : Wd;
    float sc = (seg == 0) ? SCALE_Q : 1.0f;
    int i = blockIdx.x * 256 + threadIdx.x;          // 0 .. 262143
    float4 v = reinterpret_cast<const float4*>(src)[i];
    bf16x4 o = { (__bf16)(v.x * sc), (__bf16)(v.y * sc),
                 (__bf16)(v.z * sc), (__bf16)(v.w * sc) };
    reinterpret_cast<bf16x4*>(dst)[(size_t)seg * 262144 + i] = o;
}

__global__ void pack_bias(const float* __restrict__ bq, const float* __restrict__ bk,
                          const float* __restrict__ bv, float* __restrict__ dst) {
    int i = blockIdx.x * 256 + threadIdx.x;          // 0 .. 3071
    float v = (i < 1024) ? bq[i] * SCALE_Q : (i < 2048) ? bk[i - 1024] : bv[i - 2048];
    dst[i] = v;
}

// ---------------------------------------------------------------- V transpose (LDS-tiled)
__global__ __launch_bounds__(256) void transpose_v(const __bf16* __restrict__ QKV,
                                                   __bf16* __restrict__ Vt) {
    __shared__ __bf16 t[64][66];
    const int st = blockIdx.x, bh = blockIdx.y;
    const int b = bh >> 4, h = bh & 15;
    const int tid = threadIdx.x;
    const int r = tid >> 3, c = tid & 7;
    const __bf16* src = QKV + (size_t)(b * SEQL + st * 64) * QKVLD + 2048 + h * 64;
    *(int4*)&t[r][c * 8]      = *(const int4*)(src + (size_t)r * QKVLD + c * 8);
    *(int4*)&t[r + 32][c * 8] = *(const int4*)(src + (size_t)(r + 32) * QKVLD + c * 8);
    __syncthreads();
    __bf16* dst = Vt + (size_t)bh * DH * SEQL + st * 64;
    const int d = tid >> 3;
    __bf16 tmp0[8], tmp1[8];
#pragma unroll
    for (int j = 0; j < 8; ++j) {
        tmp0[j] = t[c * 8 + j][d];
        tmp1[j] = t[c * 8 + j][d + 32];
    }
    *(int4*)(dst + (size_t)d * SEQL + c * 8)        = *(int4*)tmp0;
    *(int4*)(dst + (size_t)(d + 32) * SEQL + c * 8) = *(int4*)tmp1;
}

// ---------------------------------------------------------------- fused QKV GEMM
__global__ __launch_bounds__(256) void gemm_qkv(const __bf16* __restrict__ A,
                                                const __bf16* __restrict__ Bw,
                                                const float* __restrict__ bias,
                                                __bf16* __restrict__ C) {
    __shared__ __bf16 As[128 * 32];
    __shared__ __bf16 Bs[128 * 32];
    const int K = 1024, N = QKVLD;

    int bid = blockIdx.x;                       // 768 blocks
    int swz = (bid & 7) * 96 + (bid >> 3);      // XCD-chunked (768 % 8 == 0)
    const int bm = (swz & 31) * 128;
    const int bn = (swz >> 5) * 128;

    const int tid = threadIdx.x;
    const int w = tid >> 6, l = tid & 63, g = l >> 4, lc = l & 15;
    const int wr = (w >> 1) * 64, wc = (w & 1) * 64;
    const int row = tid >> 2, ch = tid & 3;

    const __bf16* Ap = A  + (size_t)(bm + row) * K + ch * 8;
    const __bf16* Bp = Bw + (size_t)(bn + row) * K + ch * 8;
    __bf16* AsLo = &As[w * 512];
    __bf16* AsHi = &As[2048 + w * 512];
    __bf16* BsLo = &Bs[w * 512];
    __bf16* BsHi = &Bs[2048 + w * 512];

    f32x4 acc[4][4];
    const f32x4 z4 = {0.f, 0.f, 0.f, 0.f};
#pragma unroll
    for (int i = 0; i < 4; ++i)
#pragma unroll
        for (int j = 0; j < 4; ++j) acc[i][j] = z4;

    for (int kt = 0; kt < K; kt += 32) {
        gload16(Ap + kt,                   AsLo);
        gload16(Ap + kt + (size_t)64 * K,  AsHi);
        gload16(Bp + kt,                   BsLo);
        gload16(Bp + kt + (size_t)64 * K,  BsHi);
        __syncthreads();

        bf16x8 af[4], bfr[4];
#pragma unroll
        for (int i = 0; i < 4; ++i)
            af[i] = *(const bf16x8*)&As[(wr + i * 16 + lc) * 32 + g * 8];
#pragma unroll
        for (int j = 0; j < 4; ++j)
            bfr[j] = *(const bf16x8*)&Bs[(wc + j * 16 + lc) * 32 + g * 8];
        __builtin_amdgcn_s_setprio(1);
#pragma unroll
        for (int i = 0; i < 4; ++i)
#pragma unroll
            for (int j = 0; j < 4; ++j)
                acc[i][j] = __builtin_amdgcn_mfma_f32_16x16x32_bf16(af[i], bfr[j], acc[i][j], 0, 0, 0);
        __builtin_amdgcn_s_setprio(0);
        __syncthreads();
    }

#pragma unroll
    for (int i = 0; i < 4; ++i) {
        int r0 = bm + wr + i * 16 + g * 4;
#pragma unroll
        for (int j = 0; j < 4; ++j) {
            int c = bn + wc + j * 16 + lc;
            float bb = bias[c];
#pragma unroll
            for (int r = 0; r < 4; ++r)
                C[(size_t)(r0 + r) * N + c] = (__bf16)(acc[i][j][r] + bb);
        }
    }
}

// ---------------------------------------------------------------- out GEMM
__global__ __launch_bounds__(256) void gemm_out(const __bf16* __restrict__ A,
                                                const __bf16* __restrict__ Bw,
                                                const float* __restrict__ bias,
                                                float* __restrict__ Cout) {
    __shared__ __bf16 As[128 * 32];
    __shared__ __bf16 Bs[128 * 32];
    const int N = HIDDEN, K = HIDDEN;

    const int tid = threadIdx.x;
    const int w = tid >> 6, l = tid & 63, g = l >> 4, lc = l & 15;
    const int wr = (w >> 1) * 64, wc = (w & 1) * 64;
    const int bm = blockIdx.x * 128, bn = blockIdx.y * 128;
    const int row = tid >> 2, ch = tid & 3;

    const __bf16* Arow0 = A  + (size_t)(bm + row) * K + ch * 8;
    const __bf16* Arow1 = Arow0 + (size_t)64 * K;
    const __bf16* Brow0 = Bw + (size_t)(bn + row) * K + ch * 8;
    const __bf16* Brow1 = Brow0 + (size_t)64 * K;

    f32x4 acc[4][4];
    const f32x4 z4 = {0.f, 0.f, 0.f, 0.f};
#pragma unroll
    for (int i = 0; i < 4; ++i)
#pragma unroll
        for (int j = 0; j < 4; ++j) acc[i][j] = z4;

    int4 ra0 = *(const int4*)(Arow0);
    int4 ra1 = *(const int4*)(Arow1);
    int4 rb0 = *(const int4*)(Brow0);
    int4 rb1 = *(const int4*)(Brow1);

    for (int kt = 0; kt < K; kt += 32) {
        *(int4*)&As[row * 32 + ch * 8]        = ra0;
        *(int4*)&As[(64 + row) * 32 + ch * 8] = ra1;
        *(int4*)&Bs[row * 32 + ch * 8]        = rb0;
        *(int4*)&Bs[(64 + row) * 32 + ch * 8] = rb1;
        __syncthreads();

        if (kt + 32 < K) {
            ra0 = *(const int4*)(Arow0 + kt + 32);
            ra1 = *(const int4*)(Arow1 + kt + 32);
            rb0 = *(const int4*)(Brow0 + kt + 32);
            rb1 = *(const int4*)(Brow1 + kt + 32);
        }

        bf16x8 af[4], bfr[4];
#pragma unroll
        for (int i = 0; i < 4; ++i)
            af[i] = *(const bf16x8*)&As[(wr + i * 16 + lc) * 32 + g * 8];
#pragma unroll
        for (int j = 0; j < 4; ++j)
            bfr[j] = *(const bf16x8*)&Bs[(wc + j * 16 + lc) * 32 + g * 8];
        __builtin_amdgcn_s_setprio(1);
#pragma unroll
        for (int i = 0; i < 4; ++i)
#pragma unroll
            for (int j = 0; j < 4; ++j)
                acc[i][j] = __builtin_amdgcn_mfma_f32_16x16x32_bf16(af[i], bfr[j], acc[i][j], 0, 0, 0);
        __builtin_amdgcn_s_setprio(0);
        __syncthreads();
    }

#pragma unroll
    for (int i = 0; i < 4; ++i) {
        int r0 = bm + wr + i * 16 + g * 4;
#pragma unroll
        for (int j = 0; j < 4; ++j) {
            int c = bn + wc + j * 16 + lc;
            float bb = bias[c];
#pragma unroll
            for (int r = 0; r < 4; ++r)
                Cout[(size_t)(r0 + r) * N + c] = acc[i][j][r] + bb;
        }
    }
}

// ---------------------------------------------------------------- flash attention, split-K
// grid = 1024 (XCD-swizzled): (split, bh, qt). Each block: 1024 k, 128 q, 4 waves.
// Writes UNNORMALIZED partial O (bf16, Ctx layout) + per-q (m,l) f32 pairs.
__global__ __launch_bounds__(256) void attn_kernel(const __bf16* __restrict__ QKV,
                                                   const __bf16* __restrict__ Vt,
                                                   __bf16* __restrict__ P0,
                                                   __bf16* __restrict__ P1,
                                                   float2* __restrict__ ML) {
    __shared__ __bf16 k_lds[2][64][64];   // XOR-swizzled via pre-swizzled global src
    __shared__ __bf16 v_lds[2][64][64];
    __shared__ float  bc[4][32];

    const int tid = threadIdx.x;
    const int w  = tid >> 6;
    const int l  = tid & 63;
    const int ql = l & 31;
    const int lh = l >> 5;

    int bid = blockIdx.x;                       // 1024 blocks
    int swz = (bid & 7) * 128 + (bid >> 3);     // XCD-chunked (1024 % 8 == 0)
    const int split = swz >> 9;
    const int qt = swz & 15, bh = (swz >> 4) & 31;
    const int b = bh >> 4, hd = bh & 15;
    const int qw = qt * 128 + w * 32;
    const int koff = split * KSPAN;

    const __bf16* Qg = QKV + (size_t)b * SEQL * QKVLD + hd * DH;
    const __bf16* Kg = Qg + 1024;
    const __bf16* Vg = Vt + (size_t)bh * DH * SEQL;
    __bf16* Pg = split ? P1 : P0;

    bf16x8 qf[4];
    {
        const __bf16* qp = Qg + (size_t)(qw + ql) * QKVLD + lh * 8;
#pragma unroll
        for (int c = 0; c < 4; ++c) qf[c] = *(const bf16x8*)(qp + c * 16);
    }

    const int sr   = l >> 3;
    const int gcol = ((l & 7) * 8) ^ (sr << 3);
    auto stage = [&](int kb, int nb) {
        const __bf16* kp = Kg + (size_t)(kb + w * 8 + sr) * QKVLD + gcol;
        const __bf16* vp = Vg + (size_t)(w * 8 + sr) * SEQL + kb + gcol;
        gload16(kp,                          &k_lds[nb][w * 8][0]);
        gload16(kp + (size_t)32 * QKVLD,     &k_lds[nb][32 + w * 8][0]);
        gload16(vp,                          &v_lds[nb][w * 8][0]);
        gload16(vp + (size_t)32 * SEQL,      &v_lds[nb][32 + w * 8][0]);
    };

    stage(koff, 0);
    __syncthreads();

    f32x16 o0, o1;
#pragma unroll
    for (int r = 0; r < 16; ++r) { o0[r] = 0.f; o1[r] = 0.f; }
    float m_r = -1e30f, l_r = 0.f;

    const int NT = KSPAN / 64;
    const int rsw = (ql & 7) << 3;

    for (int kt = 0; kt < NT; ++kt) {
        const int buf = kt & 1;
        const int kb = koff + kt * 64;

        if (kt + 1 < NT) stage(kb + 64, buf ^ 1);

        // ---- QK^T (swapped: A=K, B=Q)
        f32x16 sA, sB;
#pragma unroll
        for (int r = 0; r < 16; ++r) { sA[r] = 0.f; sB[r] = 0.f; }
        __builtin_amdgcn_s_setprio(1);
#pragma unroll
        for (int c = 0; c < 4; ++c) {
            bf16x8 k0 = *(const bf16x8*)&k_lds[buf][ql]     [(c * 16 + lh * 8) ^ rsw];
            bf16x8 k1 = *(const bf16x8*)&k_lds[buf][32 + ql][(c * 16 + lh * 8) ^ rsw];
            sA = __builtin_amdgcn_mfma_f32_32x32x16_bf16(k0, qf[c], sA, 0, 0, 0);
            sB = __builtin_amdgcn_mfma_f32_32x32x16_bf16(k1, qf[c], sB, 0, 0, 0);
        }
        __builtin_amdgcn_s_setprio(0);

        float p[32];
#pragma unroll
        for (int r = 0; r < 16; ++r) { p[r] = sA[r]; p[16 + r] = sB[r]; }

        // diagonal mask (wave-uniform branch; only the split containing the diagonal runs it)
        if (kb < qw + 32 && qw < kb + 64) {
            const int qg = qw + ql;
#pragma unroll
            for (int i = 0; i < 32; ++i) {
                int kg = kb + ((i >> 4) << 5) + (i & 3) + ((i >> 2) & 3) * 8 + lh * 4;
                if (kg == qg) p[i] = -1e30f;
            }
        }

        // row max: pairwise tree + cross-half
        float t16[16];
#pragma unroll
        for (int i = 0; i < 16; ++i) t16[i] = fmaxf(p[i], p[i + 16]);
#pragma unroll
        for (int i = 0; i < 8; ++i) t16[i] = fmaxf(t16[i], t16[i + 8]);
#pragma unroll
        for (int i = 0; i < 4; ++i) t16[i] = fmaxf(t16[i], t16[i + 4]);
        float pm = fmaxf(fmaxf(t16[0], t16[1]), fmaxf(t16[2], t16[3]));
        pm = fmaxf(pm, __shfl_xor(pm, 32, 64));

        // defer-max rescale (log2 domain, THR=8)
        if (__any(pm > m_r + 8.f)) {
            float mn = fmaxf(m_r, pm);
            float al = exp2fast(m_r - mn);
            m_r = mn;
            l_r *= al;
            if (lh == 0) bc[w][ql] = al;
            asm volatile("s_waitcnt lgkmcnt(0)" ::: "memory");
            float ag[16];
#pragma unroll
            for (int r = 0; r < 16; ++r)
                ag[r] = bc[w][(r & 3) + (r >> 2) * 8 + lh * 4];
#pragma unroll
            for (int r = 0; r < 16; ++r) { o0[r] *= ag[r]; o1[r] *= ag[r]; }
        }

        // exp2 + tree row-sum
#pragma unroll
        for (int i = 0; i < 32; ++i) p[i] = exp2fast(p[i] - m_r);
        float s16[16];
#pragma unroll
        for (int i = 0; i < 16; ++i) s16[i] = p[i] + p[i + 16];
#pragma unroll
        for (int i = 0; i < 8; ++i) s16[i] += s16[i + 8];
#pragma unroll
        for (int i = 0; i < 4; ++i) s16[i] += s16[i + 4];
        float rs = (s16[0] + s16[1]) + (s16[2] + s16[3]);
        rs += __shfl_xor(rs, 32, 64);
        l_r += rs;

        // P -> bf16 PV A-fragments in-register (T12)
        bf16x8 pa[4];
#pragma unroll
        for (int s = 0; s < 2; ++s) {
            unsigned w0 = cvtpk(p[s * 16 + 0],  p[s * 16 + 1]);
            unsigned w1 = cvtpk(p[s * 16 + 2],  p[s * 16 + 3]);
            unsigned w2 = cvtpk(p[s * 16 + 4],  p[s * 16 + 5]);
            unsigned w3 = cvtpk(p[s * 16 + 6],  p[s * 16 + 7]);
            unsigned w4 = cvtpk(p[s * 16 + 8],  p[s * 16 + 9]);
            unsigned w5 = cvtpk(p[s * 16 + 10], p[s * 16 + 11]);
            unsigned w6 = cvtpk(p[s * 16 + 12], p[s * 16 + 13]);
            unsigned w7 = cvtpk(p[s * 16 + 14], p[s * 16 + 15]);
            pswap(w0, w2); pswap(w1, w3);
            pswap(w4, w6); pswap(w5, w7);
            uint4 lo4 = {w0, w1, w2, w3};
            uint4 hi4 = {w4, w5, w6, w7};
            pa[s * 2 + 0] = *(bf16x8*)&lo4;
            pa[s * 2 + 1] = *(bf16x8*)&hi4;
        }

        // ---- PV
        __builtin_amdgcn_s_setprio(1);
#pragma unroll
        for (int s = 0; s < 2; ++s)
#pragma unroll
            for (int sl = 0; sl < 2; ++sl) {
                const int col = s * 32 + sl * 16 + lh * 8;
                bf16x8 v0 = *(const bf16x8*)&v_lds[buf][ql]     [col ^ rsw];
                bf16x8 v1 = *(const bf16x8*)&v_lds[buf][32 + ql][col ^ rsw];
                o0 = __builtin_amdgcn_mfma_f32_32x32x16_bf16(pa[s * 2 + sl], v0, o0, 0, 0, 0);
                o1 = __builtin_amdgcn_mfma_f32_32x32x16_bf16(pa[s * 2 + sl], v1, o1, 0, 0, 0);
            }
        __builtin_amdgcn_s_setprio(0);

        __syncthreads();
    }

    // epilogue: unnormalized partial O + (m,l)
    if (lh == 0) ML[(size_t)split * 65536 + bh * 2048 + qw + ql] = make_float2(m_r, l_r);
#pragma unroll
    for (int r = 0; r < 16; ++r) {
        int cr = (r & 3) + (r >> 2) * 8 + lh * 4;
        int qrow = qw + cr;
        __bf16* cp = Pg + (size_t)(b * SEQL + qrow) * HIDDEN + hd * DH + ql;
        cp[0]  = (__bf16)o0[r];
        cp[32] = (__bf16)o1[r];
    }
}

// ---------------------------------------------------------------- split merge (in-place over P0)
__global__ __launch_bounds__(256) void attn_merge(const __bf16* __restrict__ P1,
                                                  const float2* __restrict__ ML,
                                                  __bf16* __restrict__ Ctx /* == P0 */) {
    int idx = blockIdx.x * 256 + threadIdx.x;    // one 8-elem chunk each, 524288 total
    int e = idx * 8;
    int row = e >> 10, col = e & 1023;
    int q = row & (SEQL - 1), b = row >> 11, hd = col >> 6;
    size_t bhq = (size_t)(b * 16 + hd) * 2048 + q;
    float2 t0 = ML[bhq];
    float2 t1 = ML[65536 + bhq];
    float M = fmaxf(t0.x, t1.x);
    float a0 = exp2fast(t0.x - M), a1 = exp2fast(t1.x - M);
    float inv = 1.f / (a0 * t0.y + a1 * t1.y);
    a0 *= inv; a1 *= inv;
    bf16x8 u0 = reinterpret_cast<const bf16x8*>(Ctx)[idx];
    bf16x8 u1 = reinterpret_cast<const bf16x8*>(P1)[idx];
    bf16x8 o;
#pragma unroll
    for (int j = 0; j < 8; ++j)
        o[j] = (__bf16)((float)u0[j] * a0 + (float)u1[j] * a1);
    reinterpret_cast<bf16x8*>(Ctx)[idx] = o;
}

// ---------------------------------------------------------------- launch
extern "C" void kernel_launch(void* const* d_in, const int* in_sizes, int n_in,
                              void* d_out, int out_size, void* d_ws, size_t ws_size,
                              hipStream_t stream) {
    const float* H  = (const float*)d_in[0];
    const float* Wq = (const float*)d_in[1];
    const float* bq = (const float*)d_in[2];
    const float* Wk = (const float*)d_in[3];
    const float* bk = (const float*)d_in[4];
    const float* Wv = (const float*)d_in[5];
    const float* bv = (const float*)d_in[6];
    const float* Wd = (const float*)d_in[7];
    const float* bd = (const float*)d_in[8];
    float* out = (float*)d_out;

    char* ws = (char*)d_ws;
    const size_t MB = 1024 * 1024;
    __bf16* Hb    = (__bf16*)(ws + 0 * MB);    // 8 MB (dead after QKV gemm)
    __bf16* Ctx   = (__bf16*)(ws + 0 * MB);    // split-0 partial, merged in place
    __bf16* Wqkvb = (__bf16*)(ws + 8 * MB);    // 6 MB
    __bf16* Wdb   = (__bf16*)(ws + 14 * MB);   // 2 MB
    float*  bqkv  = (float*) (ws + 16 * MB);   // 12 KB
    __bf16* QKV   = (__bf16*)(ws + 17 * MB);   // 24 MB
    __bf16* Vtb   = (__bf16*)(ws + 41 * MB);   // 8 MB
    __bf16* P1    = (__bf16*)(ws + 49 * MB);   // 8 MB split-1 partial
    float2* ML    = (float2*)(ws + 57 * MB);   // 1 MB -> 58 MB total
    if (ws_size < 58 * MB) return;

    cvt_f32_bf16<<<4096, 256, 0, stream>>>(H, Hb, MTOT * HIDDEN / 4);
    cvt_w4<<<dim3(1024, 4), 256, 0, stream>>>(Wq, Wk, Wv, Wd, Wqkvb);
    pack_bias<<<12, 256, 0, stream>>>(bq, bk, bv, bqkv);

    gemm_qkv<<<768, 256, 0, stream>>>(Hb, Wqkvb, bqkv, QKV);

    transpose_v<<<dim3(32, 32), 256, 0, stream>>>(QKV, Vtb);

    attn_kernel<<<1024, 256, 0, stream>>>(QKV, Vtb, Ctx, P1, ML);
    attn_merge<<<2048, 256, 0, stream>>>(P1, ML, Ctx);

    gemm_out<<<dim3(32, 8), 256, 0, stream>>>(Ctx, Wdb, bd, out);
}